// Round 1
// baseline (688.742 us; speedup 1.0000x reference)
//
#include <hip/hip_runtime.h>
#include <cstdint>
#include <cstddef>

#define NB 16384
#define NA 8
#define NE 512
#define NK 1024   // 2E
#define NN 4096   // A*E

typedef __bf16 bf16x8 __attribute__((ext_vector_type(8)));
typedef float  f32x4  __attribute__((ext_vector_type(4)));

__device__ __forceinline__ uint16_t cvt_bf16(float f) {
    uint32_t u = __builtin_bit_cast(uint32_t, f);
    u += 0x7fffu + ((u >> 16) & 1u);
    return (uint16_t)(u >> 16);
}

__device__ __forceinline__ void gl_lds16(const void* g, void* l) {
    __builtin_amdgcn_global_load_lds(
        (__attribute__((address_space(1))) void*)(void*)g,
        (__attribute__((address_space(3))) void*)l, 16, 0, 0);
}

// f32 [nmat][R][C] -> bf16 [nmat][C][R]
__global__ __launch_bounds__(256) void k_tcvt(const float* __restrict__ in,
                                              uint16_t* __restrict__ out,
                                              int R, int C) {
    __shared__ float tile[32][33];
    int mat = blockIdx.z;
    int c0 = blockIdx.x * 32, r0 = blockIdx.y * 32;
    int tx = threadIdx.x & 31, ty = threadIdx.x >> 5;
    const float* src = in + (size_t)mat * R * C;
    uint16_t* dst = out + (size_t)mat * R * C;
#pragma unroll
    for (int yy = 0; yy < 4; ++yy) {
        int r = ty + yy * 8;
        tile[r][tx] = src[(size_t)(r0 + r) * C + c0 + tx];
    }
    __syncthreads();
#pragma unroll
    for (int yy = 0; yy < 4; ++yy) {
        int c = ty + yy * 8;
        dst[(size_t)(c0 + c) * R + r0 + tx] = cvt_bf16(tile[tx][c]);
    }
}

// f32 -> bf16 flat, 4 elems/thread
__global__ __launch_bounds__(256) void k_cvt4(const float* __restrict__ in,
                                              uint16_t* __restrict__ out, int n4) {
    int i = blockIdx.x * 256 + threadIdx.x;
    if (i >= n4) return;
    float4 v = ((const float4*)in)[i];
    ushort4 o;
    o.x = cvt_bf16(v.x); o.y = cvt_bf16(v.y); o.z = cvt_bf16(v.z); o.w = cvt_bf16(v.w);
    ((ushort4*)out)[i] = o;
}

// bvec[a*E+j] = sum_i lb[i] * fwd[a,i,j]   (f32)
__global__ __launch_bounds__(256) void k_bvec(const float* __restrict__ lb,
                                              const float* __restrict__ fwd,
                                              float* __restrict__ bvec) {
    int n = blockIdx.x * 256 + threadIdx.x;
    int a = n >> 9, j = n & 511;
    const float* f = fwd + (size_t)a * NE * NE + j;
    float s = 0.f;
    for (int i = 0; i < NE; ++i) s = fmaf(lb[i], f[(size_t)i * NE], s);
    bvec[n] = s;
}

// TM[m=k'(1024)][n=(a,j)(4096)] = sum_i lwT[m][i] * fwdT[n][i]; store transposed TMT[n][m] bf16
__global__ __launch_bounds__(256) void k_prep(const uint16_t* __restrict__ lwT,
                                              const uint16_t* __restrict__ fwdT,
                                              uint16_t* __restrict__ TMT) {
    __shared__ alignas(16) uint16_t lA[128 * 32];
    __shared__ alignas(16) uint16_t lB[128 * 32];
    int bz = blockIdx.x;
    int nt = bz & 31, mt = bz >> 5;
    int m0 = mt * 128, n0 = nt * 128;
    int t = threadIdx.x, lane = t & 63;
    int w = t >> 6, wm = w >> 1, wn = w & 1;
    int lr = lane & 15, lc = lane >> 4;
    f32x4 acc[4][4] = {};
    for (int k0 = 0; k0 < NE; k0 += 32) {
        __syncthreads();
#pragma unroll
        for (int p = 0; p < 2; ++p) {
            int idx = p * 256 + t;
            int row = idx >> 2, c16 = idx & 3;
            gl_lds16(lwT + (size_t)(m0 + row) * NE + k0 + c16 * 8, lA + idx * 8);
            gl_lds16(fwdT + (size_t)(n0 + row) * NE + k0 + c16 * 8, lB + idx * 8);
        }
        __syncthreads();
        bf16x8 af[4], bfr[4];
#pragma unroll
        for (int i = 0; i < 4; ++i)
            af[i] = *(const bf16x8*)&lA[(wm * 64 + i * 16 + lr) * 32 + lc * 8];
#pragma unroll
        for (int j = 0; j < 4; ++j)
            bfr[j] = *(const bf16x8*)&lB[(wn * 64 + j * 16 + lr) * 32 + lc * 8];
#pragma unroll
        for (int i = 0; i < 4; ++i)
#pragma unroll
            for (int j = 0; j < 4; ++j)
                acc[i][j] = __builtin_amdgcn_mfma_f32_16x16x32_bf16(af[i], bfr[j], acc[i][j], 0, 0, 0);
    }
#pragma unroll
    for (int i = 0; i < 4; ++i) {
        int mb = m0 + wm * 64 + i * 16 + lc * 4;
#pragma unroll
        for (int j = 0; j < 4; ++j) {
            int n = n0 + wn * 64 + j * 16 + lr;
            ushort4 v;
            v.x = cvt_bf16(acc[i][j][0]);
            v.y = cvt_bf16(acc[i][j][1]);
            v.z = cvt_bf16(acc[i][j][2]);
            v.w = cvt_bf16(acc[i][j][3]);
            *(ushort4*)&TMT[(size_t)n * NK + mb] = v;
        }
    }
}

// attr[b, a, j] = img[b,:]@TM_a[0:512] + edge[b,a,:]@TM_a[512:1024] + bvec_a[j]
__global__ __launch_bounds__(256) void k_attr(const uint16_t* __restrict__ imgb,
                                              const float* __restrict__ edge,
                                              const uint16_t* __restrict__ TMT,
                                              const float* __restrict__ bvec,
                                              float* __restrict__ attr) {
    __shared__ alignas(16) uint16_t lA[128 * 32];
    __shared__ alignas(16) uint16_t lB[128 * 32];
    int bz = blockIdx.x;
    int nt = bz & 31, mt = bz >> 5;
    int a = nt >> 2, jt = nt & 3;
    int m0 = mt * 128, jb = jt * 128;
    int ng0 = a * NE + jb;
    int t = threadIdx.x, lane = t & 63;
    int w = t >> 6, wm = w >> 1, wn = w & 1;
    int lr = lane & 15, lc = lane >> 4;
    f32x4 acc[4][4];
#pragma unroll
    for (int j = 0; j < 4; ++j) {
        float bv = bvec[ng0 + wn * 64 + j * 16 + lr];
        f32x4 b4 = {bv, bv, bv, bv};
#pragma unroll
        for (int i = 0; i < 4; ++i) acc[i][j] = b4;
    }
    for (int k0 = 0; k0 < NK; k0 += 32) {
        __syncthreads();
        if (k0 < NE) {
#pragma unroll
            for (int p = 0; p < 2; ++p) {
                int idx = p * 256 + t;
                int row = idx >> 2, c16 = idx & 3;
                gl_lds16(imgb + (size_t)(m0 + row) * NE + k0 + c16 * 8, lA + idx * 8);
            }
        } else {
#pragma unroll
            for (int p = 0; p < 4; ++p) {
                int idx = p * 256 + t;
                int row = idx >> 3, c4 = idx & 7;
                float4 v = *(const float4*)(edge + ((size_t)(m0 + row) * NA + a) * NE + (k0 - NE) + c4 * 4);
                ushort4 o;
                o.x = cvt_bf16(v.x); o.y = cvt_bf16(v.y); o.z = cvt_bf16(v.z); o.w = cvt_bf16(v.w);
                *(ushort4*)&lA[idx * 4] = o;
            }
        }
#pragma unroll
        for (int p = 0; p < 2; ++p) {
            int idx = p * 256 + t;
            int row = idx >> 2, c16 = idx & 3;
            gl_lds16(TMT + (size_t)(ng0 + row) * NK + k0 + c16 * 8, lB + idx * 8);
        }
        __syncthreads();
        bf16x8 af[4], bfr[4];
#pragma unroll
        for (int i = 0; i < 4; ++i)
            af[i] = *(const bf16x8*)&lA[(wm * 64 + i * 16 + lr) * 32 + lc * 8];
#pragma unroll
        for (int j = 0; j < 4; ++j)
            bfr[j] = *(const bf16x8*)&lB[(wn * 64 + j * 16 + lr) * 32 + lc * 8];
#pragma unroll
        for (int i = 0; i < 4; ++i)
#pragma unroll
            for (int j = 0; j < 4; ++j)
                acc[i][j] = __builtin_amdgcn_mfma_f32_16x16x32_bf16(af[i], bfr[j], acc[i][j], 0, 0, 0);
    }
#pragma unroll
    for (int i = 0; i < 4; ++i) {
#pragma unroll
        for (int r = 0; r < 4; ++r) {
            int bm = m0 + wm * 64 + i * 16 + lc * 4 + r;
            float* orow = attr + ((size_t)bm * NA + a) * NE + jb;
#pragma unroll
            for (int j = 0; j < 4; ++j)
                orow[wn * 64 + j * 16 + lr] = acc[i][j][r];
        }
    }
}

// ind[b,j] = sum_a sw[a] * relu( attr[b,a,:] @ bwd_a[:,j] )
__global__ __launch_bounds__(256) void k_ind(const float* __restrict__ attr,
                                             const uint16_t* __restrict__ bwdT,
                                             const float* __restrict__ sw,
                                             float* __restrict__ ind) {
    __shared__ alignas(16) uint16_t lA[128 * 32];
    __shared__ alignas(16) uint16_t lB[128 * 32];
    int bz = blockIdx.x;
    int jt = bz & 3, mt = bz >> 2;
    int m0 = mt * 128, jb = jt * 128;
    int t = threadIdx.x, lane = t & 63;
    int w = t >> 6, wm = w >> 1, wn = w & 1;
    int lr = lane & 15, lc = lane >> 4;
    f32x4 res[4][4] = {};
    for (int a = 0; a < NA; ++a) {
        f32x4 acc[4][4] = {};
        for (int k0 = 0; k0 < NE; k0 += 32) {
            __syncthreads();
#pragma unroll
            for (int p = 0; p < 4; ++p) {
                int idx = p * 256 + t;
                int row = idx >> 3, c4 = idx & 7;
                float4 v = *(const float4*)(attr + ((size_t)(m0 + row) * NA + a) * NE + k0 + c4 * 4);
                ushort4 o;
                o.x = cvt_bf16(v.x); o.y = cvt_bf16(v.y); o.z = cvt_bf16(v.z); o.w = cvt_bf16(v.w);
                *(ushort4*)&lA[idx * 4] = o;
            }
#pragma unroll
            for (int p = 0; p < 2; ++p) {
                int idx = p * 256 + t;
                int row = idx >> 2, c16 = idx & 3;
                gl_lds16(bwdT + ((size_t)a * NE + jb + row) * NE + k0 + c16 * 8, lB + idx * 8);
            }
            __syncthreads();
            bf16x8 af[4], bfr[4];
#pragma unroll
            for (int i = 0; i < 4; ++i)
                af[i] = *(const bf16x8*)&lA[(wm * 64 + i * 16 + lr) * 32 + lc * 8];
#pragma unroll
            for (int j = 0; j < 4; ++j)
                bfr[j] = *(const bf16x8*)&lB[(wn * 64 + j * 16 + lr) * 32 + lc * 8];
#pragma unroll
            for (int i = 0; i < 4; ++i)
#pragma unroll
                for (int j = 0; j < 4; ++j)
                    acc[i][j] = __builtin_amdgcn_mfma_f32_16x16x32_bf16(af[i], bfr[j], acc[i][j], 0, 0, 0);
        }
        float wa = sw[a];
#pragma unroll
        for (int i = 0; i < 4; ++i)
#pragma unroll
            for (int j = 0; j < 4; ++j)
#pragma unroll
                for (int r = 0; r < 4; ++r)
                    res[i][j][r] += wa * fmaxf(acc[i][j][r], 0.f);
    }
#pragma unroll
    for (int i = 0; i < 4; ++i) {
#pragma unroll
        for (int r = 0; r < 4; ++r) {
            int bm = m0 + wm * 64 + i * 16 + lc * 4 + r;
            float* orow = ind + (size_t)bm * NE + jb;
#pragma unroll
            for (int j = 0; j < 4; ++j)
                orow[wn * 64 + j * 16 + lr] = res[i][j][r];
        }
    }
}

extern "C" void kernel_launch(void* const* d_in, const int* in_sizes, int n_in,
                              void* d_out, int out_size, void* d_ws, size_t ws_size,
                              hipStream_t stream) {
    (void)in_sizes; (void)n_in; (void)out_size; (void)ws_size;
    const float* img  = (const float*)d_in[0];
    const float* edge = (const float*)d_in[1];
    const float* lw   = (const float*)d_in[2];
    const float* lb   = (const float*)d_in[3];
    const float* fwd  = (const float*)d_in[4];
    const float* bwd  = (const float*)d_in[5];
    const float* sw   = (const float*)d_in[6];
    float* attr = (float*)d_out;
    float* ind  = attr + (size_t)NB * NA * NE;

    char* ws = (char*)d_ws;
    uint16_t* lwT  = (uint16_t*)ws;  ws += (size_t)NK * NE * 2;       // 1 MB  [1024][512]
    uint16_t* fwdT = (uint16_t*)ws;  ws += (size_t)NA * NE * NE * 2;  // 4 MB  [8][j][i]
    uint16_t* bwdT = (uint16_t*)ws;  ws += (size_t)NA * NE * NE * 2;  // 4 MB  [8][j][i]
    uint16_t* TMT  = (uint16_t*)ws;  ws += (size_t)NN * NK * 2;       // 8 MB  [4096][1024]
    uint16_t* imgb = (uint16_t*)ws;  ws += (size_t)NB * NE * 2;       // 16 MB [B][512]
    float*    bvec = (float*)ws;     ws += (size_t)NN * 4;            // 16 KB

    k_tcvt<<<dim3(NK / 32, NE / 32, 1), 256, 0, stream>>>(lw, lwT, NE, NK);
    k_tcvt<<<dim3(NE / 32, NE / 32, NA), 256, 0, stream>>>(fwd, fwdT, NE, NE);
    k_tcvt<<<dim3(NE / 32, NE / 32, NA), 256, 0, stream>>>(bwd, bwdT, NE, NE);
    k_cvt4<<<NB * NE / 4 / 256, 256, 0, stream>>>(img, imgb, NB * NE / 4);
    k_bvec<<<NN / 256, 256, 0, stream>>>(lb, fwd, bvec);
    k_prep<<<(NK / 128) * (NN / 128), 256, 0, stream>>>(lwT, fwdT, TMT);
    k_attr<<<(NB / 128) * (NN / 128), 256, 0, stream>>>(imgb, edge, TMT, bvec, attr);
    k_ind<<<(NB / 128) * (NE / 128), 256, 0, stream>>>(attr, bwdT, sw, ind);
}

// Round 2
// 677.885 us; speedup vs baseline: 1.0160x; 1.0160x over previous
//
#include <hip/hip_runtime.h>
#include <cstdint>
#include <cstddef>

#define NB 16384
#define NA 8
#define NE 512
#define NK 1024   // 2E
#define NN 4096   // A*E

typedef __bf16 bf16x8 __attribute__((ext_vector_type(8)));
typedef float  f32x4  __attribute__((ext_vector_type(4)));

__device__ __forceinline__ uint16_t cvt_bf16(float f) {
    uint32_t u = __builtin_bit_cast(uint32_t, f);
    u += 0x7fffu + ((u >> 16) & 1u);
    return (uint16_t)(u >> 16);
}

// LDS chunk swizzle: 16B-chunk c within a 32-elem (64B) bf16 row, rows in tile.
// c' = c ^ ((row ^ (row>>2)) & 3)  -> frag reads conflict-free (2-way max).
__device__ __forceinline__ int swz(int row) { return (row ^ (row >> 2)) & 3; }

__device__ __forceinline__ void gl_lds16(const void* g, void* l) {
    __builtin_amdgcn_global_load_lds(
        (__attribute__((address_space(1))) void*)(void*)g,
        (__attribute__((address_space(3))) void*)l, 16, 0, 0);
}

// f32 [nmat][R][C] -> bf16 [nmat][C][R]
__global__ __launch_bounds__(256) void k_tcvt(const float* __restrict__ in,
                                              uint16_t* __restrict__ out,
                                              int R, int C) {
    __shared__ float tile[32][33];
    int mat = blockIdx.z;
    int c0 = blockIdx.x * 32, r0 = blockIdx.y * 32;
    int tx = threadIdx.x & 31, ty = threadIdx.x >> 5;
    const float* src = in + (size_t)mat * R * C;
    uint16_t* dst = out + (size_t)mat * R * C;
#pragma unroll
    for (int yy = 0; yy < 4; ++yy) {
        int r = ty + yy * 8;
        tile[r][tx] = src[(size_t)(r0 + r) * C + c0 + tx];
    }
    __syncthreads();
#pragma unroll
    for (int yy = 0; yy < 4; ++yy) {
        int c = ty + yy * 8;
        dst[(size_t)(c0 + c) * R + r0 + tx] = cvt_bf16(tile[tx][c]);
    }
}

// f32 -> bf16 flat, 4 elems/thread
__global__ __launch_bounds__(256) void k_cvt4(const float* __restrict__ in,
                                              uint16_t* __restrict__ out, int n4) {
    int i = blockIdx.x * 256 + threadIdx.x;
    if (i >= n4) return;
    float4 v = ((const float4*)in)[i];
    ushort4 o;
    o.x = cvt_bf16(v.x); o.y = cvt_bf16(v.y); o.z = cvt_bf16(v.z); o.w = cvt_bf16(v.w);
    ((ushort4*)out)[i] = o;
}

// bvec[a*E+j] += partial over 32 i's; 128 blocks, atomics (bvec pre-zeroed)
__global__ __launch_bounds__(256) void k_bvec(const float* __restrict__ lb,
                                              const float* __restrict__ fwd,
                                              float* __restrict__ bvec) {
    int a = blockIdx.x >> 4, i0 = (blockIdx.x & 15) * 32;
    int t = threadIdx.x;
    float s0 = 0.f, s1 = 0.f;
#pragma unroll 4
    for (int i = 0; i < 32; ++i) {
        float w = lb[i0 + i];
        const float* f = fwd + ((size_t)a * NE + i0 + i) * NE;
        s0 = fmaf(w, f[t], s0);
        s1 = fmaf(w, f[t + 256], s1);
    }
    atomicAdd(&bvec[a * NE + t], s0);
    atomicAdd(&bvec[a * NE + t + 256], s1);
}

// TM[m=k'(1024)][n=(a,j)(4096)] = sum_i lwT[m][i] * fwdT[n][i]; store TMT[n][m] bf16
__global__ __launch_bounds__(256) void k_prep(const uint16_t* __restrict__ lwT,
                                              const uint16_t* __restrict__ fwdT,
                                              uint16_t* __restrict__ TMT) {
    __shared__ alignas(16) uint16_t lA[128 * 32];
    __shared__ alignas(16) uint16_t lB[128 * 32];
    int bz = blockIdx.x;
    int nt = bz & 31, mt = bz >> 5;
    int m0 = mt * 128, n0 = nt * 128;
    int t = threadIdx.x, lane = t & 63;
    int w = t >> 6, wm = w >> 1, wn = w & 1;
    int lr = lane & 15, lc = lane >> 4;
    int sl = swz(lr);
    f32x4 acc[4][4] = {};
    for (int k0 = 0; k0 < NE; k0 += 32) {
        __syncthreads();
#pragma unroll
        for (int p = 0; p < 2; ++p) {
            int idx = p * 256 + t;
            int row = idx >> 2, c16 = (idx & 3) ^ swz(row);
            gl_lds16(lwT + (size_t)(m0 + row) * NE + k0 + c16 * 8, lA + idx * 8);
            gl_lds16(fwdT + (size_t)(n0 + row) * NE + k0 + c16 * 8, lB + idx * 8);
        }
        __syncthreads();
        bf16x8 af[4], bfr[4];
#pragma unroll
        for (int i = 0; i < 4; ++i)
            af[i] = *(const bf16x8*)&lA[(wm * 64 + i * 16 + lr) * 32 + ((lc ^ sl) << 3)];
#pragma unroll
        for (int j = 0; j < 4; ++j)
            bfr[j] = *(const bf16x8*)&lB[(wn * 64 + j * 16 + lr) * 32 + ((lc ^ sl) << 3)];
#pragma unroll
        for (int i = 0; i < 4; ++i)
#pragma unroll
            for (int j = 0; j < 4; ++j)
                acc[i][j] = __builtin_amdgcn_mfma_f32_16x16x32_bf16(af[i], bfr[j], acc[i][j], 0, 0, 0);
    }
#pragma unroll
    for (int i = 0; i < 4; ++i) {
        int mb = m0 + wm * 64 + i * 16 + lc * 4;
#pragma unroll
        for (int j = 0; j < 4; ++j) {
            int n = n0 + wn * 64 + j * 16 + lr;
            ushort4 v;
            v.x = cvt_bf16(acc[i][j][0]);
            v.y = cvt_bf16(acc[i][j][1]);
            v.z = cvt_bf16(acc[i][j][2]);
            v.w = cvt_bf16(acc[i][j][3]);
            *(ushort4*)&TMT[(size_t)n * NK + mb] = v;
        }
    }
}

// attr[b, a, j] = img[b,:]@TM_a[0:512] + edge[b,a,:]@TM_a[512:1024] + bvec_a[j]
__global__ __launch_bounds__(256) void k_attr(const uint16_t* __restrict__ imgb,
                                              const float* __restrict__ edge,
                                              const uint16_t* __restrict__ TMT,
                                              const float* __restrict__ bvec,
                                              float* __restrict__ attr) {
    __shared__ alignas(16) uint16_t lA[128 * 32];
    __shared__ alignas(16) uint16_t lB[128 * 32];
    int bz = blockIdx.x;
    int nt = bz & 31, mt = bz >> 5;
    int a = nt >> 2, jt = nt & 3;
    int m0 = mt * 128, jb = jt * 128;
    int ng0 = a * NE + jb;
    int t = threadIdx.x, lane = t & 63;
    int w = t >> 6, wm = w >> 1, wn = w & 1;
    int lr = lane & 15, lc = lane >> 4;
    int sl = swz(lr);
    f32x4 acc[4][4];
#pragma unroll
    for (int j = 0; j < 4; ++j) {
        float bv = bvec[ng0 + wn * 64 + j * 16 + lr];
        f32x4 b4 = {bv, bv, bv, bv};
#pragma unroll
        for (int i = 0; i < 4; ++i) acc[i][j] = b4;
    }
    for (int k0 = 0; k0 < NK; k0 += 32) {
        __syncthreads();
        if (k0 < NE) {
#pragma unroll
            for (int p = 0; p < 2; ++p) {
                int idx = p * 256 + t;
                int row = idx >> 2, c16 = (idx & 3) ^ swz(row);
                gl_lds16(imgb + (size_t)(m0 + row) * NE + k0 + c16 * 8, lA + idx * 8);
            }
        } else {
#pragma unroll
            for (int p = 0; p < 4; ++p) {
                int idx = p * 256 + t;
                int row = idx >> 3, c4 = idx & 7;
                float4 v = *(const float4*)(edge + ((size_t)(m0 + row) * NA + a) * NE + (k0 - NE) + c4 * 4);
                ushort4 o;
                o.x = cvt_bf16(v.x); o.y = cvt_bf16(v.y); o.z = cvt_bf16(v.z); o.w = cvt_bf16(v.w);
                int eo = row * 32 + ((((c4 >> 1) ^ swz(row)) << 3) + ((c4 & 1) << 2));
                *(ushort4*)&lA[eo] = o;
            }
        }
#pragma unroll
        for (int p = 0; p < 2; ++p) {
            int idx = p * 256 + t;
            int row = idx >> 2, c16 = (idx & 3) ^ swz(row);
            gl_lds16(TMT + (size_t)(ng0 + row) * NK + k0 + c16 * 8, lB + idx * 8);
        }
        __syncthreads();
        bf16x8 af[4], bfr[4];
#pragma unroll
        for (int i = 0; i < 4; ++i)
            af[i] = *(const bf16x8*)&lA[(wm * 64 + i * 16 + lr) * 32 + ((lc ^ sl) << 3)];
#pragma unroll
        for (int j = 0; j < 4; ++j)
            bfr[j] = *(const bf16x8*)&lB[(wn * 64 + j * 16 + lr) * 32 + ((lc ^ sl) << 3)];
#pragma unroll
        for (int i = 0; i < 4; ++i)
#pragma unroll
            for (int j = 0; j < 4; ++j)
                acc[i][j] = __builtin_amdgcn_mfma_f32_16x16x32_bf16(af[i], bfr[j], acc[i][j], 0, 0, 0);
    }
#pragma unroll
    for (int i = 0; i < 4; ++i) {
#pragma unroll
        for (int r = 0; r < 4; ++r) {
            int bm = m0 + wm * 64 + i * 16 + lc * 4 + r;
            float* orow = attr + ((size_t)bm * NA + a) * NE + jb;
#pragma unroll
            for (int j = 0; j < 4; ++j)
                orow[wn * 64 + j * 16 + lr] = acc[i][j][r];
        }
    }
}

// ind[b,j] = sum_a sw[a]*relu(attr[b,a,:]@bwd_a[:,j]); block = 32 rows x 512 j,
// 4 waves each 32x128; attr fetched exactly once (f32->bf16 cvt once).
__global__ __launch_bounds__(256) void k_ind(const float* __restrict__ attr,
                                             const uint16_t* __restrict__ bwdT,
                                             const float* __restrict__ sw,
                                             float* __restrict__ ind) {
    __shared__ alignas(16) uint16_t lA[32 * 32];    // 2 KB
    __shared__ alignas(16) uint16_t lB[512 * 32];   // 32 KB
    int m0 = blockIdx.x * 32;
    int t = threadIdx.x, lane = t & 63;
    int w = t >> 6;  // wave owns j in [w*128, w*128+128)
    int lr = lane & 15, lc = lane >> 4;
    int sl = swz(lr);
    int arow = t >> 3, ac4 = t & 7;  // lA reg-stage coords
    int aeo = arow * 32 + ((((ac4 >> 1) ^ swz(arow)) << 3) + ((ac4 & 1) << 2));
    f32x4 res[2][8] = {};
    for (int a = 0; a < NA; ++a) {
        float wa = sw[a];
        f32x4 acc[2][8] = {};
        for (int k0 = 0; k0 < NE; k0 += 32) {
            __syncthreads();
            // lA: 32x32 f32 tile of attr -> bf16, swizzled reg-stage
            {
                float4 v = *(const float4*)(attr + ((size_t)(m0 + arow) * NA + a) * NE + k0 + ac4 * 4);
                ushort4 o;
                o.x = cvt_bf16(v.x); o.y = cvt_bf16(v.y); o.z = cvt_bf16(v.z); o.w = cvt_bf16(v.w);
                *(ushort4*)&lA[aeo] = o;
            }
            // lB: 512x32 bf16 of bwdT via global_load_lds, swizzled source
#pragma unroll
            for (int p = 0; p < 8; ++p) {
                int idx = p * 256 + t;
                int row = idx >> 2, c16 = (idx & 3) ^ swz(row);
                gl_lds16(bwdT + ((size_t)a * NE + row) * NE + k0 + c16 * 8, lB + idx * 8);
            }
            __syncthreads();
            bf16x8 af[2], bfr[8];
#pragma unroll
            for (int i = 0; i < 2; ++i)
                af[i] = *(const bf16x8*)&lA[(i * 16 + lr) * 32 + ((lc ^ sl) << 3)];
#pragma unroll
            for (int j = 0; j < 8; ++j)
                bfr[j] = *(const bf16x8*)&lB[(w * 128 + j * 16 + lr) * 32 + ((lc ^ sl) << 3)];
#pragma unroll
            for (int i = 0; i < 2; ++i)
#pragma unroll
                for (int j = 0; j < 8; ++j)
                    acc[i][j] = __builtin_amdgcn_mfma_f32_16x16x32_bf16(af[i], bfr[j], acc[i][j], 0, 0, 0);
        }
#pragma unroll
        for (int i = 0; i < 2; ++i)
#pragma unroll
            for (int j = 0; j < 8; ++j)
#pragma unroll
                for (int r = 0; r < 4; ++r)
                    res[i][j][r] += wa * fmaxf(acc[i][j][r], 0.f);
    }
#pragma unroll
    for (int i = 0; i < 2; ++i) {
#pragma unroll
        for (int r = 0; r < 4; ++r) {
            int bm = m0 + i * 16 + lc * 4 + r;
            float* orow = ind + (size_t)bm * NE;
#pragma unroll
            for (int j = 0; j < 8; ++j)
                orow[w * 128 + j * 16 + lr] = res[i][j][r];
        }
    }
}

extern "C" void kernel_launch(void* const* d_in, const int* in_sizes, int n_in,
                              void* d_out, int out_size, void* d_ws, size_t ws_size,
                              hipStream_t stream) {
    (void)in_sizes; (void)n_in; (void)out_size; (void)ws_size;
    const float* img  = (const float*)d_in[0];
    const float* edge = (const float*)d_in[1];
    const float* lw   = (const float*)d_in[2];
    const float* lb   = (const float*)d_in[3];
    const float* fwd  = (const float*)d_in[4];
    const float* bwd  = (const float*)d_in[5];
    const float* sw   = (const float*)d_in[6];
    float* attr = (float*)d_out;
    float* ind  = attr + (size_t)NB * NA * NE;

    char* ws = (char*)d_ws;
    uint16_t* lwT  = (uint16_t*)ws;  ws += (size_t)NK * NE * 2;       // 1 MB  [1024][512]
    uint16_t* fwdT = (uint16_t*)ws;  ws += (size_t)NA * NE * NE * 2;  // 4 MB  [8][j][i]
    uint16_t* bwdT = (uint16_t*)ws;  ws += (size_t)NA * NE * NE * 2;  // 4 MB  [8][j][i]
    uint16_t* TMT  = (uint16_t*)ws;  ws += (size_t)NN * NK * 2;       // 8 MB  [4096][1024]
    uint16_t* imgb = (uint16_t*)ws;  ws += (size_t)NB * NE * 2;       // 16 MB [B][512]
    float*    bvec = (float*)ws;     ws += (size_t)NN * 4;            // 16 KB

    hipMemsetAsync(bvec, 0, (size_t)NN * 4, stream);
    k_tcvt<<<dim3(NK / 32, NE / 32, 1), 256, 0, stream>>>(lw, lwT, NE, NK);
    k_tcvt<<<dim3(NE / 32, NE / 32, NA), 256, 0, stream>>>(fwd, fwdT, NE, NE);
    k_tcvt<<<dim3(NE / 32, NE / 32, NA), 256, 0, stream>>>(bwd, bwdT, NE, NE);
    k_cvt4<<<NB * NE / 4 / 256, 256, 0, stream>>>(img, imgb, NB * NE / 4);
    k_bvec<<<128, 256, 0, stream>>>(lb, fwd, bvec);
    k_prep<<<(NK / 128) * (NN / 128), 256, 0, stream>>>(lwT, fwdT, TMT);
    k_attr<<<(NB / 128) * (NN / 128), 256, 0, stream>>>(imgb, edge, TMT, bvec, attr);
    k_ind<<<NB / 32, 256, 0, stream>>>(attr, bwdT, sw, ind);
}

// Round 3
// 534.377 us; speedup vs baseline: 1.2889x; 1.2686x over previous
//
#include <hip/hip_runtime.h>
#include <cstdint>
#include <cstddef>

#define NB 16384
#define NA 8
#define NE 512
#define NK 1024   // 2E
#define NN 4096   // A*E

typedef __bf16 bf16x8 __attribute__((ext_vector_type(8)));
typedef float  f32x4  __attribute__((ext_vector_type(4)));
typedef uint16_t u16x8 __attribute__((ext_vector_type(8)));

__device__ __forceinline__ uint16_t cvt_bf16(float f) {
    uint32_t u = __builtin_bit_cast(uint32_t, f);
    u += 0x7fffu + ((u >> 16) & 1u);
    return (uint16_t)(u >> 16);
}

// BK=32 swizzle (k_prep only): 16B-chunk c within 64B row
__device__ __forceinline__ int swz(int row) { return (row ^ (row >> 2)) & 3; }

__device__ __forceinline__ void gl_lds16(const void* g, void* l) {
    __builtin_amdgcn_global_load_lds(
        (__attribute__((address_space(1))) void*)(void*)g,
        (__attribute__((address_space(3))) void*)l, 16, 0, 0);
}

// f32 [nmat][R][C] -> bf16 [nmat][C][R]
__global__ __launch_bounds__(256) void k_tcvt(const float* __restrict__ in,
                                              uint16_t* __restrict__ out,
                                              int R, int C) {
    __shared__ float tile[32][33];
    int mat = blockIdx.z;
    int c0 = blockIdx.x * 32, r0 = blockIdx.y * 32;
    int tx = threadIdx.x & 31, ty = threadIdx.x >> 5;
    const float* src = in + (size_t)mat * R * C;
    uint16_t* dst = out + (size_t)mat * R * C;
#pragma unroll
    for (int yy = 0; yy < 4; ++yy) {
        int r = ty + yy * 8;
        tile[r][tx] = src[(size_t)(r0 + r) * C + c0 + tx];
    }
    __syncthreads();
#pragma unroll
    for (int yy = 0; yy < 4; ++yy) {
        int c = ty + yy * 8;
        dst[(size_t)(c0 + c) * R + r0 + tx] = cvt_bf16(tile[tx][c]);
    }
}

// f32 -> bf16 flat, 4 elems/thread
__global__ __launch_bounds__(256) void k_cvt4(const float* __restrict__ in,
                                              uint16_t* __restrict__ out, int n4) {
    int i = blockIdx.x * 256 + threadIdx.x;
    if (i >= n4) return;
    float4 v = ((const float4*)in)[i];
    ushort4 o;
    o.x = cvt_bf16(v.x); o.y = cvt_bf16(v.y); o.z = cvt_bf16(v.z); o.w = cvt_bf16(v.w);
    ((ushort4*)out)[i] = o;
}

// bvec[a*E+j] += partial over 32 i's; 128 blocks, atomics (bvec pre-zeroed)
__global__ __launch_bounds__(256) void k_bvec(const float* __restrict__ lb,
                                              const float* __restrict__ fwd,
                                              float* __restrict__ bvec) {
    int a = blockIdx.x >> 4, i0 = (blockIdx.x & 15) * 32;
    int t = threadIdx.x;
    float s0 = 0.f, s1 = 0.f;
#pragma unroll 4
    for (int i = 0; i < 32; ++i) {
        float w = lb[i0 + i];
        const float* f = fwd + ((size_t)a * NE + i0 + i) * NE;
        s0 = fmaf(w, f[t], s0);
        s1 = fmaf(w, f[t + 256], s1);
    }
    atomicAdd(&bvec[a * NE + t], s0);
    atomicAdd(&bvec[a * NE + t + 256], s1);
}

// TM[m=k'(1024)][n=(a,j)(4096)] = sum_i lwT[m][i]*fwdT[n][i]; store TMT[n][m] bf16
__global__ __launch_bounds__(256) void k_prep(const uint16_t* __restrict__ lwT,
                                              const uint16_t* __restrict__ fwdT,
                                              uint16_t* __restrict__ TMT) {
    __shared__ alignas(16) uint16_t lA[128 * 32];
    __shared__ alignas(16) uint16_t lB[128 * 32];
    int bz = blockIdx.x;
    int nt = bz & 31, mt = bz >> 5;
    int m0 = mt * 128, n0 = nt * 128;
    int t = threadIdx.x, lane = t & 63;
    int w = t >> 6, wm = w >> 1, wn = w & 1;
    int lr = lane & 15, lc = lane >> 4;
    int sl = swz(lr);
    f32x4 acc[4][4] = {};
    for (int k0 = 0; k0 < NE; k0 += 32) {
        __syncthreads();
#pragma unroll
        for (int p = 0; p < 2; ++p) {
            int idx = p * 256 + t;
            int row = idx >> 2, c16 = (idx & 3) ^ swz(row);
            gl_lds16(lwT + (size_t)(m0 + row) * NE + k0 + c16 * 8, lA + idx * 8);
            gl_lds16(fwdT + (size_t)(n0 + row) * NE + k0 + c16 * 8, lB + idx * 8);
        }
        __syncthreads();
        bf16x8 af[4], bfr[4];
#pragma unroll
        for (int i = 0; i < 4; ++i)
            af[i] = *(const bf16x8*)&lA[(wm * 64 + i * 16 + lr) * 32 + ((lc ^ sl) << 3)];
#pragma unroll
        for (int j = 0; j < 4; ++j)
            bfr[j] = *(const bf16x8*)&lB[(wn * 64 + j * 16 + lr) * 32 + ((lc ^ sl) << 3)];
#pragma unroll
        for (int i = 0; i < 4; ++i)
#pragma unroll
            for (int j = 0; j < 4; ++j)
                acc[i][j] = __builtin_amdgcn_mfma_f32_16x16x32_bf16(af[i], bfr[j], acc[i][j], 0, 0, 0);
    }
#pragma unroll
    for (int i = 0; i < 4; ++i) {
        int mb = m0 + wm * 64 + i * 16 + lc * 4;
#pragma unroll
        for (int j = 0; j < 4; ++j) {
            int n = n0 + wn * 64 + j * 16 + lr;
            ushort4 v;
            v.x = cvt_bf16(acc[i][j][0]);
            v.y = cvt_bf16(acc[i][j][1]);
            v.z = cvt_bf16(acc[i][j][2]);
            v.w = cvt_bf16(acc[i][j][3]);
            *(ushort4*)&TMT[(size_t)n * NK + mb] = v;
        }
    }
}

// attr[b,a,j] = img[b]@TM_a[0:512] + edge[b,a]@TM_a[512:1024] + bvec_a[j]
// BK=64, swizzle chunk^=(row&7). Optionally also writes bf16 attrb.
template<bool EDGEB, bool WB>
__global__ __launch_bounds__(256) void k_mm(const uint16_t* __restrict__ imgb,
                                            const float* __restrict__ edgef,
                                            const uint16_t* __restrict__ edgeb,
                                            const uint16_t* __restrict__ TMT,
                                            const float* __restrict__ bvec,
                                            float* __restrict__ attr,
                                            uint16_t* __restrict__ attrb) {
    __shared__ alignas(16) uint16_t lA[128 * 64];
    __shared__ alignas(16) uint16_t lB[128 * 64];
    int bz = blockIdx.x;
    int nt = bz & 31, mt = bz >> 5;
    int a = nt >> 2, jt = nt & 3;
    int m0 = mt * 128, jb = jt * 128;
    int t = threadIdx.x, lane = t & 63;
    int w = t >> 6, wm = w >> 1, wn = w & 1;
    int lr = lane & 15, lc = lane >> 4;
    f32x4 acc[4][4];
#pragma unroll
    for (int j = 0; j < 4; ++j) {
        float bv = bvec[a * NE + jb + wn * 64 + j * 16 + lr];
        f32x4 b4 = {bv, bv, bv, bv};
#pragma unroll
        for (int i = 0; i < 4; ++i) acc[i][j] = b4;
    }
    for (int k0 = 0; k0 < NK; k0 += 64) {
        __syncthreads();
        if (k0 < NE) {
#pragma unroll
            for (int p = 0; p < 4; ++p) {
                int idx = p * 256 + t;
                int row = idx >> 3, cg = (idx & 7) ^ (row & 7);
                gl_lds16(imgb + (size_t)(m0 + row) * NE + k0 + cg * 8, lA + idx * 8);
            }
        } else if (EDGEB) {
#pragma unroll
            for (int p = 0; p < 4; ++p) {
                int idx = p * 256 + t;
                int row = idx >> 3, cg = (idx & 7) ^ (row & 7);
                gl_lds16(edgeb + ((size_t)(m0 + row) * NA + a) * NE + (k0 - NE) + cg * 8, lA + idx * 8);
            }
        } else {
#pragma unroll
            for (int p = 0; p < 4; ++p) {
                int idx = p * 256 + t;
                int row = idx >> 3, c = idx & 7, cg = c ^ (row & 7);
                const float* s = edgef + ((size_t)(m0 + row) * NA + a) * NE + (k0 - NE) + c * 8;
                float4 v0 = ((const float4*)s)[0];
                float4 v1 = ((const float4*)s)[1];
                u16x8 o = {cvt_bf16(v0.x), cvt_bf16(v0.y), cvt_bf16(v0.z), cvt_bf16(v0.w),
                           cvt_bf16(v1.x), cvt_bf16(v1.y), cvt_bf16(v1.z), cvt_bf16(v1.w)};
                *(u16x8*)&lA[row * 64 + cg * 8] = o;
            }
        }
#pragma unroll
        for (int p = 0; p < 4; ++p) {
            int idx = p * 256 + t;
            int row = idx >> 3, cg = (idx & 7) ^ (row & 7);
            gl_lds16(TMT + (size_t)(a * NE + jb + row) * NK + k0 + cg * 8, lB + idx * 8);
        }
        __syncthreads();
#pragma unroll
        for (int h = 0; h < 2; ++h) {
            bf16x8 af[4], bfr[4];
#pragma unroll
            for (int i = 0; i < 4; ++i)
                af[i] = *(const bf16x8*)&lA[(wm * 64 + i * 16 + lr) * 64 + (((h * 4 + lc) ^ (lr & 7)) << 3)];
#pragma unroll
            for (int j = 0; j < 4; ++j)
                bfr[j] = *(const bf16x8*)&lB[(wn * 64 + j * 16 + lr) * 64 + (((h * 4 + lc) ^ (lr & 7)) << 3)];
#pragma unroll
            for (int i = 0; i < 4; ++i)
#pragma unroll
                for (int j = 0; j < 4; ++j)
                    acc[i][j] = __builtin_amdgcn_mfma_f32_16x16x32_bf16(af[i], bfr[j], acc[i][j], 0, 0, 0);
        }
    }
#pragma unroll
    for (int i = 0; i < 4; ++i) {
#pragma unroll
        for (int r = 0; r < 4; ++r) {
            int bm = m0 + wm * 64 + i * 16 + lc * 4 + r;
            float* orow = attr + ((size_t)bm * NA + a) * NE + jb;
#pragma unroll
            for (int j = 0; j < 4; ++j)
                orow[wn * 64 + j * 16 + lr] = acc[i][j][r];
            if (WB) {
                uint16_t* brow = attrb + ((size_t)bm * NA + a) * NE + jb;
#pragma unroll
                for (int j = 0; j < 4; ++j)
                    brow[wn * 64 + j * 16 + lr] = cvt_bf16(acc[i][j][r]);
            }
        }
    }
}

// ind[b,j] = sum_a sw[a]*relu(attr[b,a,:]@bwd_a[:,j]); 128x128 tiles, a-loop inside
template<bool AB>
__global__ __launch_bounds__(256) void k_ind2(const float* __restrict__ attrf,
                                              const uint16_t* __restrict__ attrb,
                                              const uint16_t* __restrict__ bwdT,
                                              const float* __restrict__ sw,
                                              float* __restrict__ ind) {
    __shared__ alignas(16) uint16_t lA[128 * 64];
    __shared__ alignas(16) uint16_t lB[128 * 64];
    int bz = blockIdx.x;
    int jt = bz & 3, mt = bz >> 2;
    int m0 = mt * 128, jb = jt * 128;
    int t = threadIdx.x, lane = t & 63;
    int w = t >> 6, wm = w >> 1, wn = w & 1;
    int lr = lane & 15, lc = lane >> 4;
    f32x4 res[4][4] = {};
    for (int a = 0; a < NA; ++a) {
        float wa = sw[a];
        f32x4 acc[4][4] = {};
        for (int k0 = 0; k0 < NE; k0 += 64) {
            __syncthreads();
            if (AB) {
#pragma unroll
                for (int p = 0; p < 4; ++p) {
                    int idx = p * 256 + t;
                    int row = idx >> 3, cg = (idx & 7) ^ (row & 7);
                    gl_lds16(attrb + ((size_t)(m0 + row) * NA + a) * NE + k0 + cg * 8, lA + idx * 8);
                }
            } else {
#pragma unroll
                for (int p = 0; p < 4; ++p) {
                    int idx = p * 256 + t;
                    int row = idx >> 3, c = idx & 7, cg = c ^ (row & 7);
                    const float* s = attrf + ((size_t)(m0 + row) * NA + a) * NE + k0 + c * 8;
                    float4 v0 = ((const float4*)s)[0];
                    float4 v1 = ((const float4*)s)[1];
                    u16x8 o = {cvt_bf16(v0.x), cvt_bf16(v0.y), cvt_bf16(v0.z), cvt_bf16(v0.w),
                               cvt_bf16(v1.x), cvt_bf16(v1.y), cvt_bf16(v1.z), cvt_bf16(v1.w)};
                    *(u16x8*)&lA[row * 64 + cg * 8] = o;
                }
            }
#pragma unroll
            for (int p = 0; p < 4; ++p) {
                int idx = p * 256 + t;
                int row = idx >> 3, cg = (idx & 7) ^ (row & 7);
                gl_lds16(bwdT + (size_t)(a * NE + jb + row) * NE + k0 + cg * 8, lB + idx * 8);
            }
            __syncthreads();
#pragma unroll
            for (int h = 0; h < 2; ++h) {
                bf16x8 af[4], bfr[4];
#pragma unroll
                for (int i = 0; i < 4; ++i)
                    af[i] = *(const bf16x8*)&lA[(wm * 64 + i * 16 + lr) * 64 + (((h * 4 + lc) ^ (lr & 7)) << 3)];
#pragma unroll
                for (int j = 0; j < 4; ++j)
                    bfr[j] = *(const bf16x8*)&lB[(wn * 64 + j * 16 + lr) * 64 + (((h * 4 + lc) ^ (lr & 7)) << 3)];
#pragma unroll
                for (int i = 0; i < 4; ++i)
#pragma unroll
                    for (int j = 0; j < 4; ++j)
                        acc[i][j] = __builtin_amdgcn_mfma_f32_16x16x32_bf16(af[i], bfr[j], acc[i][j], 0, 0, 0);
            }
        }
#pragma unroll
        for (int i = 0; i < 4; ++i)
#pragma unroll
            for (int j = 0; j < 4; ++j)
#pragma unroll
                for (int r = 0; r < 4; ++r)
                    res[i][j][r] += wa * fmaxf(acc[i][j][r], 0.f);
    }
#pragma unroll
    for (int i = 0; i < 4; ++i) {
#pragma unroll
        for (int r = 0; r < 4; ++r) {
            int bm = m0 + wm * 64 + i * 16 + lc * 4 + r;
            float* orow = ind + (size_t)bm * NE + jb;
#pragma unroll
            for (int j = 0; j < 4; ++j)
                orow[wn * 64 + j * 16 + lr] = res[i][j][r];
        }
    }
}

extern "C" void kernel_launch(void* const* d_in, const int* in_sizes, int n_in,
                              void* d_out, int out_size, void* d_ws, size_t ws_size,
                              hipStream_t stream) {
    (void)in_sizes; (void)n_in; (void)out_size;
    const float* img  = (const float*)d_in[0];
    const float* edge = (const float*)d_in[1];
    const float* lw   = (const float*)d_in[2];
    const float* lb   = (const float*)d_in[3];
    const float* fwd  = (const float*)d_in[4];
    const float* bwd  = (const float*)d_in[5];
    const float* sw   = (const float*)d_in[6];
    float* attr = (float*)d_out;
    float* ind  = attr + (size_t)NB * NA * NE;

    char* ws = (char*)d_ws;
    size_t off = 0;
    auto alloc = [&](size_t bytes) { void* p = ws + off; off += bytes; return p; };
    uint16_t* lwT  = (uint16_t*)alloc((size_t)NK * NE * 2);       // 1 MB
    uint16_t* fwdT = (uint16_t*)alloc((size_t)NA * NE * NE * 2);  // 4 MB
    uint16_t* bwdT = (uint16_t*)alloc((size_t)NA * NE * NE * 2);  // 4 MB
    uint16_t* TMT  = (uint16_t*)alloc((size_t)NN * NK * 2);       // 8 MB
    uint16_t* imgb = (uint16_t*)alloc((size_t)NB * NE * 2);       // 16 MB
    float*    bvec = (float*)alloc((size_t)NN * 4);               // 16 KB

    const size_t BIGB = (size_t)NB * NA * NE * 2;  // 128 MB each
    bool has_attrb = ws_size >= off + BIGB;
    uint16_t* attrb = has_attrb ? (uint16_t*)alloc(BIGB) : (uint16_t*)0;
    bool has_edgeb = ws_size >= off + BIGB;
    uint16_t* edgeb = has_edgeb ? (uint16_t*)alloc(BIGB) : (uint16_t*)0;

    hipMemsetAsync(bvec, 0, (size_t)NN * 4, stream);
    k_tcvt<<<dim3(NK / 32, NE / 32, 1), 256, 0, stream>>>(lw, lwT, NE, NK);
    k_tcvt<<<dim3(NE / 32, NE / 32, NA), 256, 0, stream>>>(fwd, fwdT, NE, NE);
    k_tcvt<<<dim3(NE / 32, NE / 32, NA), 256, 0, stream>>>(bwd, bwdT, NE, NE);
    k_cvt4<<<NB * NE / 4 / 256, 256, 0, stream>>>(img, imgb, NB * NE / 4);
    if (has_edgeb)
        k_cvt4<<<NB * NA * NE / 4 / 256, 256, 0, stream>>>(edge, edgeb, NB * NA * NE / 4);
    k_bvec<<<128, 256, 0, stream>>>(lb, fwd, bvec);
    k_prep<<<(NK / 128) * (NN / 128), 256, 0, stream>>>(lwT, fwdT, TMT);

    int mm_grid = (NB / 128) * (NN / 128);
    if (has_edgeb && has_attrb)
        k_mm<true, true><<<mm_grid, 256, 0, stream>>>(imgb, edge, edgeb, TMT, bvec, attr, attrb);
    else if (has_edgeb)
        k_mm<true, false><<<mm_grid, 256, 0, stream>>>(imgb, edge, edgeb, TMT, bvec, attr, attrb);
    else if (has_attrb)
        k_mm<false, true><<<mm_grid, 256, 0, stream>>>(imgb, edge, edgeb, TMT, bvec, attr, attrb);
    else
        k_mm<false, false><<<mm_grid, 256, 0, stream>>>(imgb, edge, edgeb, TMT, bvec, attr, attrb);

    int ind_grid = (NB / 128) * (NE / 128);
    if (has_attrb)
        k_ind2<true><<<ind_grid, 256, 0, stream>>>(attr, attrb, bwdT, sw, ind);
    else
        k_ind2<false><<<ind_grid, 256, 0, stream>>>(attr, attrb, bwdT, sw, ind);
}

// Round 4
// 511.201 us; speedup vs baseline: 1.3473x; 1.0453x over previous
//
#include <hip/hip_runtime.h>
#include <cstdint>
#include <cstddef>

#define NB 16384
#define NA 8
#define NE 512
#define NK 1024   // 2E
#define NN 4096   // A*E

typedef __bf16 bf16x8 __attribute__((ext_vector_type(8)));
typedef float  f32x4  __attribute__((ext_vector_type(4)));
typedef uint16_t u16x8 __attribute__((ext_vector_type(8)));

__device__ __forceinline__ uint16_t cvt_bf16(float f) {
    uint32_t u = __builtin_bit_cast(uint32_t, f);
    u += 0x7fffu + ((u >> 16) & 1u);
    return (uint16_t)(u >> 16);
}

// BK=32 chunk swizzle: 16B-chunk c within 64B row; proven 0-conflict (R3 PMC)
__device__ __forceinline__ int swz(int row) { return (row ^ (row >> 2)) & 3; }

__device__ __forceinline__ void gl_lds16(const void* g, void* l) {
    __builtin_amdgcn_global_load_lds(
        (__attribute__((address_space(1))) void*)(void*)g,
        (__attribute__((address_space(3))) void*)l, 16, 0, 0);
}

// f32 [nmat][R][C] -> bf16 [nmat][C][R]
__global__ __launch_bounds__(256) void k_tcvt(const float* __restrict__ in,
                                              uint16_t* __restrict__ out,
                                              int R, int C) {
    __shared__ float tile[32][33];
    int mat = blockIdx.z;
    int c0 = blockIdx.x * 32, r0 = blockIdx.y * 32;
    int tx = threadIdx.x & 31, ty = threadIdx.x >> 5;
    const float* src = in + (size_t)mat * R * C;
    uint16_t* dst = out + (size_t)mat * R * C;
#pragma unroll
    for (int yy = 0; yy < 4; ++yy) {
        int r = ty + yy * 8;
        tile[r][tx] = src[(size_t)(r0 + r) * C + c0 + tx];
    }
    __syncthreads();
#pragma unroll
    for (int yy = 0; yy < 4; ++yy) {
        int c = ty + yy * 8;
        dst[(size_t)(c0 + c) * R + r0 + tx] = cvt_bf16(tile[tx][c]);
    }
}

// f32 -> bf16 flat, 4 elems/thread
__global__ __launch_bounds__(256) void k_cvt4(const float* __restrict__ in,
                                              uint16_t* __restrict__ out, int n4) {
    int i = blockIdx.x * 256 + threadIdx.x;
    if (i >= n4) return;
    float4 v = ((const float4*)in)[i];
    ushort4 o;
    o.x = cvt_bf16(v.x); o.y = cvt_bf16(v.y); o.z = cvt_bf16(v.z); o.w = cvt_bf16(v.w);
    ((ushort4*)out)[i] = o;
}

// bvec[a*E+j] += partial over 32 i's; 128 blocks, atomics (bvec pre-zeroed)
__global__ __launch_bounds__(256) void k_bvec(const float* __restrict__ lb,
                                              const float* __restrict__ fwd,
                                              float* __restrict__ bvec) {
    int a = blockIdx.x >> 4, i0 = (blockIdx.x & 15) * 32;
    int t = threadIdx.x;
    float s0 = 0.f, s1 = 0.f;
#pragma unroll 4
    for (int i = 0; i < 32; ++i) {
        float w = lb[i0 + i];
        const float* f = fwd + ((size_t)a * NE + i0 + i) * NE;
        s0 = fmaf(w, f[t], s0);
        s1 = fmaf(w, f[t + 256], s1);
    }
    atomicAdd(&bvec[a * NE + t], s0);
    atomicAdd(&bvec[a * NE + t + 256], s1);
}

// TM[m=k'(1024)][n=(a,j)(4096)] = sum_i lwT[m][i]*fwdT[n][i]; store TMT[n][m] bf16
__global__ __launch_bounds__(256) void k_prep(const uint16_t* __restrict__ lwT,
                                              const uint16_t* __restrict__ fwdT,
                                              uint16_t* __restrict__ TMT) {
    __shared__ alignas(16) uint16_t lA[128 * 32];
    __shared__ alignas(16) uint16_t lB[128 * 32];
    int bz = blockIdx.x;
    int nt = bz & 31, mt = bz >> 5;
    int m0 = mt * 128, n0 = nt * 128;
    int t = threadIdx.x, lane = t & 63;
    int w = t >> 6, wm = w >> 1, wn = w & 1;
    int lr = lane & 15, lc = lane >> 4;
    int sl = swz(lr);
    f32x4 acc[4][4] = {};
    for (int k0 = 0; k0 < NE; k0 += 32) {
        __syncthreads();
#pragma unroll
        for (int p = 0; p < 2; ++p) {
            int idx = p * 256 + t;
            int row = idx >> 2, c16 = (idx & 3) ^ swz(row);
            gl_lds16(lwT + (size_t)(m0 + row) * NE + k0 + c16 * 8, lA + idx * 8);
            gl_lds16(fwdT + (size_t)(n0 + row) * NE + k0 + c16 * 8, lB + idx * 8);
        }
        __syncthreads();
        bf16x8 af[4], bfr[4];
#pragma unroll
        for (int i = 0; i < 4; ++i)
            af[i] = *(const bf16x8*)&lA[(wm * 64 + i * 16 + lr) * 32 + ((lc ^ sl) << 3)];
#pragma unroll
        for (int j = 0; j < 4; ++j)
            bfr[j] = *(const bf16x8*)&lB[(wn * 64 + j * 16 + lr) * 32 + ((lc ^ sl) << 3)];
#pragma unroll
        for (int i = 0; i < 4; ++i)
#pragma unroll
            for (int j = 0; j < 4; ++j)
                acc[i][j] = __builtin_amdgcn_mfma_f32_16x16x32_bf16(af[i], bfr[j], acc[i][j], 0, 0, 0);
    }
#pragma unroll
    for (int i = 0; i < 4; ++i) {
        int mb = m0 + wm * 64 + i * 16 + lc * 4;
#pragma unroll
        for (int j = 0; j < 4; ++j) {
            int n = n0 + wn * 64 + j * 16 + lr;
            ushort4 v;
            v.x = cvt_bf16(acc[i][j][0]);
            v.y = cvt_bf16(acc[i][j][1]);
            v.z = cvt_bf16(acc[i][j][2]);
            v.w = cvt_bf16(acc[i][j][3]);
            *(ushort4*)&TMT[(size_t)n * NK + mb] = v;
        }
    }
}

// attr[b,a,j] = img[b]@TM_a[0:512] + edge[b,a]@TM_a[512:1024] + bvec_a[j]
// BK=32, double-buffered 2-phase; a = XCD (each XCD owns one attribute slice)
template<bool EDGEB, bool WB>
__global__ __launch_bounds__(256) void k_mm(const uint16_t* __restrict__ imgb,
                                            const float* __restrict__ edgef,
                                            const uint16_t* __restrict__ edgeb,
                                            const uint16_t* __restrict__ TMT,
                                            const float* __restrict__ bvec,
                                            float* __restrict__ attr,
                                            uint16_t* __restrict__ attrb) {
    __shared__ alignas(16) uint16_t lA[2][128 * 32];
    __shared__ alignas(16) uint16_t lB[2][128 * 32];
    int o = blockIdx.x;            // 4096 = 8 xcd * 512
    int xcd = o & 7, idx = o >> 3; // idx 0..511
    int a = xcd, jt = idx & 3, mt = idx >> 2;
    int m0 = mt * 128, jb = jt * 128;
    int t = threadIdx.x, lane = t & 63;
    int w = t >> 6, wm = w >> 1, wn = w & 1;
    int lr = lane & 15, lc = lane >> 4;
    int sl = swz(lr);
    int srow[2], scol[2];
#pragma unroll
    for (int p = 0; p < 2; ++p) {
        int id = p * 256 + t;
        srow[p] = id >> 2;
        scol[p] = ((id & 3) ^ swz(id >> 2)) << 3;
    }
    f32x4 acc[4][4];
#pragma unroll
    for (int j = 0; j < 4; ++j) {
        float bv = bvec[a * NE + jb + wn * 64 + j * 16 + lr];
        f32x4 b4 = {bv, bv, bv, bv};
#pragma unroll
        for (int i = 0; i < 4; ++i) acc[i][j] = b4;
    }
    auto stage = [&](int buf, int s) {
        int k0 = s * 32;
        if (k0 < NE) {
#pragma unroll
            for (int p = 0; p < 2; ++p)
                gl_lds16(imgb + (size_t)(m0 + srow[p]) * NE + k0 + scol[p],
                         &lA[buf][(p * 256 + t) * 8]);
        } else if (EDGEB) {
#pragma unroll
            for (int p = 0; p < 2; ++p)
                gl_lds16(edgeb + ((size_t)(m0 + srow[p]) * NA + a) * NE + (k0 - NE) + scol[p],
                         &lA[buf][(p * 256 + t) * 8]);
        } else {
#pragma unroll
            for (int p = 0; p < 2; ++p) {
                const float* sp = edgef + ((size_t)(m0 + srow[p]) * NA + a) * NE + (k0 - NE) + scol[p];
                float4 v0 = ((const float4*)sp)[0];
                float4 v1 = ((const float4*)sp)[1];
                u16x8 ov = {cvt_bf16(v0.x), cvt_bf16(v0.y), cvt_bf16(v0.z), cvt_bf16(v0.w),
                            cvt_bf16(v1.x), cvt_bf16(v1.y), cvt_bf16(v1.z), cvt_bf16(v1.w)};
                *(u16x8*)&lA[buf][(p * 256 + t) * 8] = ov;
            }
        }
#pragma unroll
        for (int p = 0; p < 2; ++p)
            gl_lds16(TMT + (size_t)(a * NE + jb + srow[p]) * NK + k0 + scol[p],
                     &lB[buf][(p * 256 + t) * 8]);
    };
    stage(0, 0);
    __syncthreads();
    for (int s = 0; s < 32; ++s) {
        int cur = s & 1;
        if (s + 1 < 32) stage(cur ^ 1, s + 1);
        bf16x8 af[4], bfr[4];
#pragma unroll
        for (int i = 0; i < 4; ++i)
            af[i] = *(const bf16x8*)&lA[cur][(wm * 64 + i * 16 + lr) * 32 + ((lc ^ sl) << 3)];
#pragma unroll
        for (int j = 0; j < 4; ++j)
            bfr[j] = *(const bf16x8*)&lB[cur][(wn * 64 + j * 16 + lr) * 32 + ((lc ^ sl) << 3)];
#pragma unroll
        for (int i = 0; i < 4; ++i)
#pragma unroll
            for (int j = 0; j < 4; ++j)
                acc[i][j] = __builtin_amdgcn_mfma_f32_16x16x32_bf16(af[i], bfr[j], acc[i][j], 0, 0, 0);
        __syncthreads();
    }
#pragma unroll
    for (int i = 0; i < 4; ++i) {
#pragma unroll
        for (int r = 0; r < 4; ++r) {
            int bm = m0 + wm * 64 + i * 16 + lc * 4 + r;
            float* orow = attr + ((size_t)bm * NA + a) * NE + jb;
#pragma unroll
            for (int j = 0; j < 4; ++j)
                orow[wn * 64 + j * 16 + lr] = acc[i][j][r];
            if (WB) {
                uint16_t* brow = attrb + ((size_t)bm * NA + a) * NE + jb;
#pragma unroll
                for (int j = 0; j < 4; ++j)
                    brow[wn * 64 + j * 16 + lr] = cvt_bf16(acc[i][j][r]);
            }
        }
    }
}

// ind[b,j] += sum_{a in half} sw[a]*relu(attr[b,a,:]@bwd_a[:,j])
// BK=32 2-phase dbuf; (jt,ah) = XCD; a-split 2 with atomicAdd (ind pre-zeroed)
template<bool AB>
__global__ __launch_bounds__(256) void k_ind2(const float* __restrict__ attrf,
                                              const uint16_t* __restrict__ attrb,
                                              const uint16_t* __restrict__ bwdT,
                                              const float* __restrict__ sw,
                                              float* __restrict__ ind) {
    __shared__ alignas(16) uint16_t lA[2][128 * 32];
    __shared__ alignas(16) uint16_t lB[2][128 * 32];
    int o = blockIdx.x;            // 1024 = 8 xcd * 128
    int xcd = o & 7, mt = o >> 3;  // mt 0..127
    int jt = xcd >> 1, ah = xcd & 1;
    int m0 = mt * 128, jb = jt * 128, a0 = ah * 4;
    int t = threadIdx.x, lane = t & 63;
    int w = t >> 6, wm = w >> 1, wn = w & 1;
    int lr = lane & 15, lc = lane >> 4;
    int sl = swz(lr);
    int srow[2], scol[2];
#pragma unroll
    for (int p = 0; p < 2; ++p) {
        int id = p * 256 + t;
        srow[p] = id >> 2;
        scol[p] = ((id & 3) ^ swz(id >> 2)) << 3;
    }
    f32x4 res[4][4] = {};
    f32x4 acc[4][4] = {};
    auto stage = [&](int buf, int s) {
        int a = a0 + (s >> 4), kk = (s & 15) * 32;
        if (AB) {
#pragma unroll
            for (int p = 0; p < 2; ++p)
                gl_lds16(attrb + ((size_t)(m0 + srow[p]) * NA + a) * NE + kk + scol[p],
                         &lA[buf][(p * 256 + t) * 8]);
        } else {
#pragma unroll
            for (int p = 0; p < 2; ++p) {
                const float* sp = attrf + ((size_t)(m0 + srow[p]) * NA + a) * NE + kk + scol[p];
                float4 v0 = ((const float4*)sp)[0];
                float4 v1 = ((const float4*)sp)[1];
                u16x8 ov = {cvt_bf16(v0.x), cvt_bf16(v0.y), cvt_bf16(v0.z), cvt_bf16(v0.w),
                            cvt_bf16(v1.x), cvt_bf16(v1.y), cvt_bf16(v1.z), cvt_bf16(v1.w)};
                *(u16x8*)&lA[buf][(p * 256 + t) * 8] = ov;
            }
        }
#pragma unroll
        for (int p = 0; p < 2; ++p)
            gl_lds16(bwdT + (size_t)(a * NE + jb + srow[p]) * NE + kk + scol[p],
                     &lB[buf][(p * 256 + t) * 8]);
    };
    stage(0, 0);
    __syncthreads();
    for (int s = 0; s < 64; ++s) {
        int cur = s & 1;
        if (s + 1 < 64) stage(cur ^ 1, s + 1);
        bf16x8 af[4], bfr[4];
#pragma unroll
        for (int i = 0; i < 4; ++i)
            af[i] = *(const bf16x8*)&lA[cur][(wm * 64 + i * 16 + lr) * 32 + ((lc ^ sl) << 3)];
#pragma unroll
        for (int j = 0; j < 4; ++j)
            bfr[j] = *(const bf16x8*)&lB[cur][(wn * 64 + j * 16 + lr) * 32 + ((lc ^ sl) << 3)];
#pragma unroll
        for (int i = 0; i < 4; ++i)
#pragma unroll
            for (int j = 0; j < 4; ++j)
                acc[i][j] = __builtin_amdgcn_mfma_f32_16x16x32_bf16(af[i], bfr[j], acc[i][j], 0, 0, 0);
        if ((s & 15) == 15) {
            float wa = sw[a0 + (s >> 4)];
#pragma unroll
            for (int i = 0; i < 4; ++i)
#pragma unroll
                for (int j = 0; j < 4; ++j) {
#pragma unroll
                    for (int r = 0; r < 4; ++r)
                        res[i][j][r] += wa * fmaxf(acc[i][j][r], 0.f);
                    acc[i][j] = (f32x4){0.f, 0.f, 0.f, 0.f};
                }
        }
        __syncthreads();
    }
#pragma unroll
    for (int i = 0; i < 4; ++i) {
#pragma unroll
        for (int r = 0; r < 4; ++r) {
            int bm = m0 + wm * 64 + i * 16 + lc * 4 + r;
            float* orow = ind + (size_t)bm * NE + jb;
#pragma unroll
            for (int j = 0; j < 4; ++j)
                atomicAdd(&orow[wn * 64 + j * 16 + lr], res[i][j][r]);
        }
    }
}

extern "C" void kernel_launch(void* const* d_in, const int* in_sizes, int n_in,
                              void* d_out, int out_size, void* d_ws, size_t ws_size,
                              hipStream_t stream) {
    (void)in_sizes; (void)n_in; (void)out_size;
    const float* img  = (const float*)d_in[0];
    const float* edge = (const float*)d_in[1];
    const float* lw   = (const float*)d_in[2];
    const float* lb   = (const float*)d_in[3];
    const float* fwd  = (const float*)d_in[4];
    const float* bwd  = (const float*)d_in[5];
    const float* sw   = (const float*)d_in[6];
    float* attr = (float*)d_out;
    float* ind  = attr + (size_t)NB * NA * NE;

    char* ws = (char*)d_ws;
    size_t off = 0;
    auto alloc = [&](size_t bytes) { void* p = ws + off; off += bytes; return p; };
    uint16_t* lwT  = (uint16_t*)alloc((size_t)NK * NE * 2);       // 1 MB
    uint16_t* fwdT = (uint16_t*)alloc((size_t)NA * NE * NE * 2);  // 4 MB
    uint16_t* bwdT = (uint16_t*)alloc((size_t)NA * NE * NE * 2);  // 4 MB
    uint16_t* TMT  = (uint16_t*)alloc((size_t)NN * NK * 2);       // 8 MB
    uint16_t* imgb = (uint16_t*)alloc((size_t)NB * NE * 2);       // 16 MB
    float*    bvec = (float*)alloc((size_t)NN * 4);               // 16 KB

    const size_t BIGB = (size_t)NB * NA * NE * 2;  // 128 MB each
    bool has_attrb = ws_size >= off + BIGB;
    uint16_t* attrb = has_attrb ? (uint16_t*)alloc(BIGB) : (uint16_t*)0;
    bool has_edgeb = ws_size >= off + BIGB;
    uint16_t* edgeb = has_edgeb ? (uint16_t*)alloc(BIGB) : (uint16_t*)0;

    hipMemsetAsync(bvec, 0, (size_t)NN * 4, stream);
    hipMemsetAsync(ind, 0, (size_t)NB * NE * 4, stream);
    k_tcvt<<<dim3(NK / 32, NE / 32, 1), 256, 0, stream>>>(lw, lwT, NE, NK);
    k_tcvt<<<dim3(NE / 32, NE / 32, NA), 256, 0, stream>>>(fwd, fwdT, NE, NE);
    k_tcvt<<<dim3(NE / 32, NE / 32, NA), 256, 0, stream>>>(bwd, bwdT, NE, NE);
    k_cvt4<<<NB * NE / 4 / 256, 256, 0, stream>>>(img, imgb, NB * NE / 4);
    if (has_edgeb)
        k_cvt4<<<NB * NA * NE / 4 / 256, 256, 0, stream>>>(edge, edgeb, NB * NA * NE / 4);
    k_bvec<<<128, 256, 0, stream>>>(lb, fwd, bvec);
    k_prep<<<(NK / 128) * (NN / 128), 256, 0, stream>>>(lwT, fwdT, TMT);

    int mm_grid = (NB / 128) * (NN / 128);
    if (has_edgeb && has_attrb)
        k_mm<true, true><<<mm_grid, 256, 0, stream>>>(imgb, edge, edgeb, TMT, bvec, attr, attrb);
    else if (has_edgeb)
        k_mm<true, false><<<mm_grid, 256, 0, stream>>>(imgb, edge, edgeb, TMT, bvec, attr, attrb);
    else if (has_attrb)
        k_mm<false, true><<<mm_grid, 256, 0, stream>>>(imgb, edge, edgeb, TMT, bvec, attr, attrb);
    else
        k_mm<false, false><<<mm_grid, 256, 0, stream>>>(imgb, edge, edgeb, TMT, bvec, attr, attrb);

    int ind_grid = (NB / 128) * (NE / 128) * 2;  // a-split 2
    if (has_attrb)
        k_ind2<true><<<ind_grid, 256, 0, stream>>>(attr, attrb, bwdT, sw, ind);
    else
        k_ind2<false><<<ind_grid, 256, 0, stream>>>(attr, attrb, bwdT, sw, ind);
}